// Round 12
// baseline (216.142 us; speedup 1.0000x reference)
//
#include <hip/hip_runtime.h>
#include <stdint.h>

#define ASG __attribute__((address_space(1)))
#define ASL __attribute__((address_space(3)))

typedef __bf16 bf16x8 __attribute__((ext_vector_type(8)));
typedef float f32x4 __attribute__((ext_vector_type(4)));

__device__ __forceinline__ unsigned short f2bf(float f) {
  unsigned int u = __builtin_bit_cast(unsigned int, f);
  u = (u + 0x7fffu + ((u >> 16) & 1u)) >> 16;
  return (unsigned short)u;
}

// ---------------- fused prep: converts X,Wq,Wk,Wv to bf16 + bias concat ----------------
__global__ __launch_bounds__(256) void k_prep(
    const float* __restrict__ X, const float* __restrict__ Wq,
    const float* __restrict__ Wk, const float* __restrict__ Wv,
    const float* __restrict__ bq, const float* __restrict__ bk,
    const float* __restrict__ bv,
    unsigned short* __restrict__ Xb, float* __restrict__ biasF) {
  const int bid = blockIdx.x, tid = threadIdx.x;
  unsigned short* Wb = Xb + 8388608;
  if (bid < 11264) {
    const float* src;
    ushort4* dst;
    int j;
    if (bid < 8192) {
      j = bid * 256 + tid; src = X; dst = (ushort4*)Xb;
    } else {
      int w = (bid - 8192) >> 10;
      j = ((bid - 8192) & 1023) * 256 + tid;
      src = (w == 0) ? Wq : (w == 1 ? Wk : Wv);
      dst = (ushort4*)(Wb + (long)w * 1048576);
    }
    float4 v = reinterpret_cast<const float4*>(src)[j];
    ushort4 o;
    o.x = f2bf(v.x); o.y = f2bf(v.y); o.z = f2bf(v.z); o.w = f2bf(v.w);
    dst[j] = o;
  } else {
    int i = (bid - 11264) * 256 + tid;
    if (i < 3072)
      biasF[i] = (i < 1024) ? bq[i] : (i < 2048 ? bk[i - 1024] : bv[i - 2048]);
  }
}

// =====================================================================
// m201-style 8-phase NT GEMM. BM=256, BN=NF*64 (NF in {2,3,4}), BK=64,
// 8 waves (2M x 4N), wave-tile 128 x NF*16, 2-buffer LDS.
// IDENTICAL schedule to round-9 gemm8p (verified correct, absmax 3.9e-3).
// Round-12 changes ONLY: __launch_bounds__(512,1) — round 9's (512,2)
// clamped VGPR to 128 vs ~214-254 live => acc spilled to scratch
// (VGPR_Count=128 + FETCH 141MB vs 87MB proved it); 32-bit staging offsets.
// OUT_MODE: 0=bf16 store, 1=f32 store.
// =====================================================================
template <int NF, int OUT_MODE, int BIAS>
__global__ __launch_bounds__(512, 1) void gemm8p(
    const unsigned short* __restrict__ A, const unsigned short* __restrict__ B,
    void* __restrict__ Cv, const float* __restrict__ bias,
    int lda, int ldb, int ldc, int K, float alpha,
    long sA, long sB, long sC) {
  constexpr int QN0 = (NF + 1) / 2, QN1 = NF - QN0;
  constexpr int BUFSZ = 32768 + NF * 8192;
  __shared__ __align__(16) char smem[2 * BUFSZ];
  const int tid = threadIdx.x, wid = tid >> 6, lane = tid & 63;
  const int wr = wid >> 2, wc = wid & 3;
  const int bm0 = blockIdx.y << 8, bn0 = blockIdx.x * (NF * 64);
  A += (long)blockIdx.z * sA;
  B += (long)blockIdx.z * sB;
  const int NT = K >> 6;

  const int srow = tid >> 3;
  const int scol = ((tid & 7) ^ (srow & 7)) << 3;

  // ---- staging: sources (32-bit elem offsets; all matrices < 2^31 elems) ----
  int srcA_[2][2];
#pragma unroll
  for (int h = 0; h < 2; ++h)
#pragma unroll
    for (int j = 0; j < 2; ++j)
      srcA_[h][j] = (bm0 + j * 128 + h * 64 + srow) * lda + scol;
  int srcB_[2][2];
  {
    if constexpr (QN0 == 2) {
#pragma unroll
      for (int j = 0; j < 2; ++j) {
        int u = j * 64 + srow;
        srcB_[0][j] = (bn0 + (u >> 5) * (NF * 16) + (u & 31)) * ldb + scol;
      }
    } else {
      srcB_[0][0] = (bn0 + (srow >> 4) * (NF * 16) + (srow & 15)) * ldb + scol;
      srcB_[0][1] = srcB_[0][0];
    }
    if constexpr (QN1 == 2) {
#pragma unroll
      for (int j = 0; j < 2; ++j) {
        int u = j * 64 + srow;
        srcB_[1][j] = (bn0 + (u >> 5) * (NF * 16) + QN0 * 16 + (u & 31)) * ldb + scol;
      }
    } else {
      srcB_[1][0] = (bn0 + (srow >> 4) * (NF * 16) + QN0 * 16 + (srow & 15)) * ldb + scol;
      srcB_[1][1] = srcB_[1][0];
    }
  }

#define GL(SRC, DST) __builtin_amdgcn_global_load_lds((ASG const void*)(SRC), (ASL void*)(DST), 16, 0, 0)
#define STG_AH(H, KT, BUF) do { int kk = (KT); if (kk >= NT) kk -= NT; int ko = kk << 6;   \
    GL(A + (long)(srcA_[H][0] + ko), smem + (BUF) + (H) * 16384 + wid * 1024);             \
    GL(A + (long)(srcA_[H][1] + ko), smem + (BUF) + (H) * 16384 + 8192 + wid * 1024); } while (0)
#define STG_BH(H, KT, BUF) do { int kk = (KT); if (kk >= NT) kk -= NT; int ko = kk << 6;   \
    GL(B + (long)(srcB_[H][0] + ko), smem + (BUF) + 32768 + (H) * QN0 * 8192 + wid * 1024); \
    if constexpr (((H) ? QN1 : QN0) == 2)                                                   \
      GL(B + (long)(srcB_[H][1] + ko), smem + (BUF) + 32768 + (H) * QN0 * 8192 + 8192 + wid * 1024); } while (0)

  // ---- ds_read byte offsets ----
  const int L = lane & 15;
  int aoff[8], boff[NF];
#pragma unroll
  for (int mf = 0; mf < 8; ++mf) {
    int row = (mf < 4) ? (wr * 64 + mf * 16 + L) : (128 + wr * 64 + (mf - 4) * 16 + L);
    aoff[mf] = row << 7;
  }
#pragma unroll
  for (int nf = 0; nf < NF; ++nf) {
    int row = (nf < QN0) ? (wc * (QN0 * 16) + nf * 16 + L)
                         : (QN0 * 64 + wc * (QN1 * 16) + (nf - QN0) * 16 + L);
    boff[nf] = 32768 + (row << 7);
  }
  int colk[2];
#pragma unroll
  for (int ks = 0; ks < 2; ++ks)
    colk[ks] = (((ks << 2) + (lane >> 4)) ^ (lane & 7)) << 4;

  bf16x8 afr[8][2];
  bf16x8 bfr[NF][2];
  f32x4 acc[8][NF] = {};

#define RDA(BUF, MLO) do { _Pragma("unroll") for (int mf = (MLO); mf < (MLO) + 4; ++mf) \
    _Pragma("unroll") for (int ks = 0; ks < 2; ++ks)                                    \
      afr[mf][ks] = *(const bf16x8*)(smem + (BUF) + aoff[mf] + colk[ks]); } while (0)
#define RDB(BUF, NLO, NHI) do { _Pragma("unroll") for (int nf = (NLO); nf < (NHI); ++nf) \
    _Pragma("unroll") for (int ks = 0; ks < 2; ++ks)                                     \
      bfr[nf][ks] = *(const bf16x8*)(smem + (BUF) + boff[nf] + colk[ks]); } while (0)
#define MMQ(MLO, NLO, NHI) do { _Pragma("unroll") for (int mf = (MLO); mf < (MLO) + 4; ++mf) \
    _Pragma("unroll") for (int nf = (NLO); nf < (NHI); ++nf)                                 \
    _Pragma("unroll") for (int ks = 0; ks < 2; ++ks)                                         \
      acc[mf][nf] = __builtin_amdgcn_mfma_f32_16x16x32_bf16(                                 \
          afr[mf][ks], bfr[nf][ks], acc[mf][nf], 0, 0, 0); } while (0)

#define BAR() __builtin_amdgcn_s_barrier()
#define LGKM0() asm volatile("s_waitcnt lgkmcnt(0)" ::: "memory")
#define VMW() do { if constexpr (QN0 == 2) asm volatile("s_waitcnt vmcnt(6)" ::: "memory"); \
                   else asm volatile("s_waitcnt vmcnt(5)" ::: "memory"); } while (0)
#define PRIO1() __builtin_amdgcn_s_setprio(1)
#define PRIO0() __builtin_amdgcn_s_setprio(0)

  // ---- prologue: buf0 <- tile0 (full), buf1 <- tile1 {Ah0,Ah1,Bh0} ----
  STG_AH(0, 0, 0); STG_AH(1, 0, 0); STG_BH(0, 0, 0); STG_BH(1, 0, 0);
  STG_AH(0, 1, BUFSZ); STG_AH(1, 1, BUFSZ); STG_BH(0, 1, BUFSZ);
  VMW();
  BAR();

  const int NI = NT >> 1;
  for (int i = 0; i < NI; ++i) {
    const int t = 2 * i;
    // ph1
    RDA(0, 0); RDB(0, 0, QN0);
    STG_BH(1, t + 1, BUFSZ);
    BAR(); LGKM0(); PRIO1(); MMQ(0, 0, QN0); PRIO0(); BAR();
    // ph2
    RDA(0, 4);
    STG_AH(0, t + 2, 0);
    BAR(); LGKM0(); PRIO1(); MMQ(4, 0, QN0); PRIO0(); BAR();
    // ph3
    RDB(0, QN0, NF);
    STG_AH(1, t + 2, 0);
    BAR(); LGKM0(); PRIO1(); MMQ(0, QN0, NF); PRIO0(); BAR();
    // ph4
    STG_BH(0, t + 2, 0);
    BAR(); LGKM0(); PRIO1(); MMQ(4, QN0, NF); PRIO0(); VMW(); BAR();
    // ph5
    RDA(BUFSZ, 0); RDB(BUFSZ, 0, QN0);
    STG_BH(1, t + 2, 0);
    BAR(); LGKM0(); PRIO1(); MMQ(0, 0, QN0); PRIO0(); BAR();
    // ph6
    RDA(BUFSZ, 4);
    STG_AH(0, t + 3, BUFSZ);
    BAR(); LGKM0(); PRIO1(); MMQ(4, 0, QN0); PRIO0(); BAR();
    // ph7
    RDB(BUFSZ, QN0, NF);
    STG_AH(1, t + 3, BUFSZ);
    BAR(); LGKM0(); PRIO1(); MMQ(0, QN0, NF); PRIO0(); BAR();
    // ph8
    STG_BH(0, t + 3, BUFSZ);
    BAR(); LGKM0(); PRIO1(); MMQ(4, QN0, NF); PRIO0(); VMW(); BAR();
  }

  // ---- epilogue: C write (D: col=lane&15, row=(lane>>4)*4+j) ----
  const int r0 = bm0 + wr * 128 + ((lane >> 4) << 2);
  const int c0 = bn0 + wc * (NF * 16) + (lane & 15);
#pragma unroll
  for (int mf = 0; mf < 8; ++mf)
#pragma unroll
    for (int nf = 0; nf < NF; ++nf) {
      const int row0 = r0 + mf * 16;
      const int col = c0 + nf * 16;
      f32x4 v = acc[mf][nf];
      const float bb = BIAS ? bias[col] : 0.0f;
      if (OUT_MODE == 0) {
        unsigned short* C = (unsigned short*)Cv + (long)blockIdx.z * sC;
#pragma unroll
        for (int j = 0; j < 4; ++j)
          C[(long)(row0 + j) * ldc + col] = f2bf(v[j] * alpha + bb);
      } else {
        float* C = (float*)Cv + (long)blockIdx.z * sC;
#pragma unroll
        for (int j = 0; j < 4; ++j)
          C[(long)(row0 + j) * ldc + col] = v[j] * alpha + bb;
      }
    }
#undef GL
#undef STG_AH
#undef STG_BH
#undef RDA
#undef RDB
#undef MMQ
#undef BAR
#undef LGKM0
#undef VMW
#undef PRIO1
#undef PRIO0
}

// ---------------- row softmax on bf16 scores, in place ----------------
__global__ __launch_bounds__(256) void k_softmax_bf16(unsigned short* __restrict__ S) {
  long row = blockIdx.x;
  unsigned short* R = S + row * 2048;
  int t = threadIdx.x;
  int wid = t >> 6, lane = t & 63;
  uint4 raw = reinterpret_cast<const uint4*>(R)[t];
  unsigned int w[4] = {raw.x, raw.y, raw.z, raw.w};
  float v[8];
#pragma unroll
  for (int j = 0; j < 4; ++j) {
    v[2 * j]     = __builtin_bit_cast(float, (unsigned int)(w[j] << 16));
    v[2 * j + 1] = __builtin_bit_cast(float, (unsigned int)(w[j] & 0xffff0000u));
  }
  float m = v[0];
#pragma unroll
  for (int j = 1; j < 8; ++j) m = fmaxf(m, v[j]);
#pragma unroll
  for (int off = 32; off >= 1; off >>= 1) m = fmaxf(m, __shfl_xor(m, off));
  __shared__ float red[8];
  if (lane == 0) red[wid] = m;
  __syncthreads();
  m = fmaxf(fmaxf(red[0], red[1]), fmaxf(red[2], red[3]));

  float e[8], s = 0.f;
#pragma unroll
  for (int j = 0; j < 8; ++j) { e[j] = __expf(v[j] - m); s += e[j]; }
#pragma unroll
  for (int off = 32; off >= 1; off >>= 1) s += __shfl_xor(s, off);
  if (lane == 0) red[4 + wid] = s;
  __syncthreads();
  s = red[4] + red[5] + red[6] + red[7];
  float inv = 1.0f / s;

  uint4 o;
  unsigned int* ow = &o.x;
#pragma unroll
  for (int j = 0; j < 4; ++j)
    ow[j] = (unsigned int)f2bf(e[2 * j] * inv) |
            ((unsigned int)f2bf(e[2 * j + 1] * inv) << 16);
  reinterpret_cast<uint4*>(R)[t] = o;
}

// ---------------- V [b][s][h] (stride 3072) -> Vt [b][h][s] ----------------
__global__ __launch_bounds__(256) void k_transpose_v(const unsigned short* __restrict__ V,
                                                     unsigned short* __restrict__ Vt) {
  __shared__ unsigned short tile[32][33];
  int b = blockIdx.z;
  int s0 = blockIdx.y * 32, h0 = blockIdx.x * 32;
  const unsigned short* Vb = V + (long)b * 2048 * 3072;
  unsigned short* Vtb = Vt + (long)b * 1024 * 2048;
  int tx = threadIdx.x & 31, ty = threadIdx.x >> 5;
#pragma unroll
  for (int i = 0; i < 4; ++i)
    tile[ty + 8 * i][tx] = Vb[(long)(s0 + ty + 8 * i) * 3072 + h0 + tx];
  __syncthreads();
#pragma unroll
  for (int i = 0; i < 4; ++i)
    Vtb[(long)(h0 + ty + 8 * i) * 2048 + s0 + tx] = tile[tx][ty + 8 * i];
}

extern "C" void kernel_launch(void* const* d_in, const int* in_sizes, int n_in,
                              void* d_out, int out_size, void* d_ws, size_t ws_size,
                              hipStream_t stream) {
  const float* X  = (const float*)d_in[0];
  const float* Wq = (const float*)d_in[1];
  const float* bq = (const float*)d_in[2];
  const float* Wk = (const float*)d_in[3];
  const float* bk = (const float*)d_in[4];
  const float* Wv = (const float*)d_in[5];
  const float* bv = (const float*)d_in[6];
  float* out = (float*)d_out;
  (void)in_sizes; (void)n_in; (void)out_size; (void)ws_size;

  constexpr long S = 2048, H = 1024;
  constexpr long MS = 4 * S;

  size_t off = 0;
  auto alloc = [&](size_t bytes) { char* p = (char*)d_ws + off; off += bytes; return p; };
  unsigned short* Xb    = (unsigned short*)alloc(MS * H * 2);
  unsigned short* Wb    = (unsigned short*)alloc(3 * H * H * 2);
  float*          biasF = (float*)alloc(3 * H * 4);
  unsigned short* QKVb  = (unsigned short*)alloc(MS * 3 * H * 2);
  unsigned short* Vt    = (unsigned short*)alloc(4 * H * S * 2);
  unsigned short* Sb    = (unsigned short*)alloc(4 * S * S * 2);
  (void)Wb;

  // 1) fused converts + bias
  k_prep<<<dim3(11276), 256, 0, stream>>>(X, Wq, Wk, Wv, bq, bk, bv, Xb, biasF);

  // 2) fused QKV = X @ [Wq|Wk|Wv]^T + b  (M=8192, N=3072, K=1024) — NF=3, 512 blocks = 2.0 rounds
  gemm8p<3, 0, 1><<<dim3(16, 32, 1), 512, 0, stream>>>(Xb, Xb + MS * H, QKVb, biasF,
                                                       1024, 1024, 3072, 1024, 1.0f, 0, 0, 0);

  // 3) scores = Q @ K^T / 32  (per batch 2048x2048, K=1024) — NF=4, 256 blocks = 1.0 round
  gemm8p<4, 0, 0><<<dim3(8, 8, 4), 512, 0, stream>>>(QKVb, QKVb + 1024, Sb, nullptr,
                                                     3072, 3072, 2048, 1024, 0.03125f,
                                                     S * 3 * H, S * 3 * H, S * S);

  // 4) softmax rows in place (bf16)
  k_softmax_bf16<<<dim3((int)MS), 256, 0, stream>>>(Sb);

  // 5) V^T (from fused QKV, col offset 2048)
  k_transpose_v<<<dim3(32, 64, 4), 256, 0, stream>>>(QKVb + 2048, Vt);

  // 6) O = P @ V  (per batch M=2048, N=1024, K=2048) — NF=2, 256 blocks = 1.0 round
  gemm8p<2, 1, 0><<<dim3(8, 8, 4), 512, 0, stream>>>(Sb, Vt, out, nullptr,
                                                     2048, 2048, 1024, 2048, 1.0f,
                                                     S * S, H * S, S * H);
}

// Round 15
// 157.889 us; speedup vs baseline: 1.3690x; 1.3690x over previous
//
#include <hip/hip_runtime.h>
#include <stdint.h>

#define ASG __attribute__((address_space(1)))
#define ASL __attribute__((address_space(3)))

typedef __bf16 bf16x8 __attribute__((ext_vector_type(8)));
typedef float f32x4 __attribute__((ext_vector_type(4)));

__device__ __forceinline__ unsigned short f2bf(float f) {
  unsigned int u = __builtin_bit_cast(unsigned int, f);
  u = (u + 0x7fffu + ((u >> 16) & 1u)) >> 16;
  return (unsigned short)u;
}

// ---------------- fused prep: converts X,Wq,Wk,Wv to bf16 + bias concat ----------------
__global__ __launch_bounds__(256) void k_prep(
    const float* __restrict__ X, const float* __restrict__ Wq,
    const float* __restrict__ Wk, const float* __restrict__ Wv,
    const float* __restrict__ bq, const float* __restrict__ bk,
    const float* __restrict__ bv,
    unsigned short* __restrict__ Xb, float* __restrict__ biasF) {
  const int bid = blockIdx.x, tid = threadIdx.x;
  unsigned short* Wb = Xb + 8388608;
  if (bid < 11264) {
    const float* src;
    ushort4* dst;
    int j;
    if (bid < 8192) {
      j = bid * 256 + tid; src = X; dst = (ushort4*)Xb;
    } else {
      int w = (bid - 8192) >> 10;
      j = ((bid - 8192) & 1023) * 256 + tid;
      src = (w == 0) ? Wq : (w == 1 ? Wk : Wv);
      dst = (ushort4*)(Wb + (long)w * 1048576);
    }
    float4 v = reinterpret_cast<const float4*>(src)[j];
    ushort4 o;
    o.x = f2bf(v.x); o.y = f2bf(v.y); o.z = f2bf(v.z); o.w = f2bf(v.w);
    dst[j] = o;
  } else {
    int i = (bid - 11264) * 256 + tid;
    if (i < 3072)
      biasF[i] = (i < 1024) ? bq[i] : (i < 2048 ? bk[i - 1024] : bv[i - 2048]);
  }
}

// =====================================================================
// R8-proven 2-barrier GEMM: 128x256 tile, BK=64, 8 waves (2Mx4N, wave-tile
// 64x64), 3-buffer LDS ring (144KB), ONE barrier per K-tile, counted lgkmcnt
// between ds_read and MFMA, next-tile A+B01 prefetched after the barrier,
// vmcnt(6) = ring-distance-2 staging.
// C[m][n] = alpha * sum_k A[m][k]*B[n][k] (+bias[n])
// Swizzle: 16B-block-in-row ^= (row&7) on global SOURCE + ds_read (both-sides).
// OUT_MODE: 0=bf16, 1=f32, 3=bf16 but V-cols (bn0>=2048) -> VtOut[b][h][s].
// SWZ: 1D grid, lid&7 = XCD slot; batch bz = (lid&7)>>1 so each XCD-pair's
// L2 caches one batch's 4MB B-panel; bijective for per-batch count even.
// =====================================================================
template <int OUT_MODE, int BIAS, int SWZ>
__global__ __launch_bounds__(512, 2) void gemm3p(
    const unsigned short* __restrict__ A, const unsigned short* __restrict__ B,
    void* __restrict__ Cv, const float* __restrict__ bias,
    unsigned short* __restrict__ VtOut, int nx,
    int lda, int ldb, int ldc, int K, float alpha,
    long sA, long sB, long sC) {
  __shared__ __align__(16) char smem[147456];
  const int tid = threadIdx.x;
  const int wid = tid >> 6, lane = tid & 63;
  const int wr = wid >> 2, wc = wid & 3;
  int bx, by, bz;
  if constexpr (SWZ) {
    const int lid = blockIdx.x;
    const int xcd = lid & 7;
    bz = xcd >> 1;
    const int idx = ((lid >> 3) << 1) + (xcd & 1);
    bx = idx % nx;
    by = idx / nx;
  } else {
    bx = blockIdx.x; by = blockIdx.y; bz = blockIdx.z;
  }
  const int bm0 = by << 7, bn0 = bx << 8;
  A += (long)bz * sA;
  B += (long)bz * sB;
  const int NT = K >> 6;  // 64-wide K tiles

  // ---- staging source addresses (per-lane), swizzle pre-applied ----
  const int srow = tid >> 3;                         // 0..63 within a unit
  const int scol = (((tid & 7) ^ (srow & 7)) << 3);  // element col within 64
  long gA[2], gB[4];
#pragma unroll
  for (int u = 0; u < 2; ++u)
    gA[u] = (long)(bm0 + u * 64 + srow) * lda + scol;
#pragma unroll
  for (int u = 0; u < 4; ++u)
    gB[u] = (long)(bn0 + u * 64 + srow) * ldb + scol;

#define STG(PTR, GOFF, KK, LDSOFF)                                             \
  __builtin_amdgcn_global_load_lds((ASG const void*)((PTR) + (GOFF) + ((KK) << 6)), \
      (ASL void*)(smem + (LDSOFF) + wid * 1024), 16, 0, 0)

#define STG_ALL(KK, SB_) do { int kk = (KK); if (kk >= NT) kk -= NT;           \
    STG(A, gA[0], kk, (SB_));                                                  \
    STG(A, gA[1], kk, (SB_) + 8192);                                           \
    STG(B, gB[0], kk, (SB_) + 16384);                                          \
    STG(B, gB[1], kk, (SB_) + 24576);                                          \
    STG(B, gB[2], kk, (SB_) + 32768);                                          \
    STG(B, gB[3], kk, (SB_) + 40960); } while (0)

  // ---- ds_read addresses ----
  const int arow0 = (wr * 64 + (lane & 15)) << 7;           // byte, + mf*2048
  const int brow0 = 16384 + ((wc * 64 + (lane & 15)) << 7); // byte, + nf*2048
  int colk[2];
#pragma unroll
  for (int ks = 0; ks < 2; ++ks)
    colk[ks] = (((ks << 2) + (lane >> 4)) ^ (lane & 7)) << 4;

  bf16x8 afr2[4][2];
  bf16x8 b01f[2][2], b23f[2][2];
  f32x4 acc[4][4] = {};

#define RDA(CB) do { _Pragma("unroll") for (int mf = 0; mf < 4; ++mf)          \
    _Pragma("unroll") for (int ks = 0; ks < 2; ++ks)                           \
      afr2[mf][ks] = *(const bf16x8*)(smem + (CB) + arow0 + (mf << 11) + colk[ks]); } while (0)
#define RDB01(CB) do { _Pragma("unroll") for (int nf = 0; nf < 2; ++nf)        \
    _Pragma("unroll") for (int ks = 0; ks < 2; ++ks)                           \
      b01f[nf][ks] = *(const bf16x8*)(smem + (CB) + brow0 + (nf << 11) + colk[ks]); } while (0)
#define RDB23(CB) do { _Pragma("unroll") for (int nf = 0; nf < 2; ++nf)        \
    _Pragma("unroll") for (int ks = 0; ks < 2; ++ks)                           \
      b23f[nf][ks] = *(const bf16x8*)(smem + (CB) + brow0 + ((nf + 2) << 11) + colk[ks]); } while (0)

#define MM(BF, NB) do {                                                        \
    _Pragma("unroll") for (int mf = 0; mf < 4; ++mf)                           \
    _Pragma("unroll") for (int nf = 0; nf < 2; ++nf)                           \
    _Pragma("unroll") for (int ks = 0; ks < 2; ++ks)                           \
      acc[mf][(NB) + nf] = __builtin_amdgcn_mfma_f32_16x16x32_bf16(            \
          afr2[mf][ks], BF[nf][ks], acc[mf][(NB) + nf], 0, 0, 0); } while (0)

  // ---- prologue: tile0 -> buf0, tile1 -> buf1; certify tile0; prefetch reads ----
  STG_ALL(0, 0);
  STG_ALL(1, 49152);
  asm volatile("s_waitcnt vmcnt(6)" ::: "memory");
  __builtin_amdgcn_s_barrier();
  RDA(0); RDB01(0);

  int bc = 0, bs = 2 * 49152;
  for (int t = 0; t < NT; ++t) {
    RDB23(bc);
    STG_ALL(t + 2, bs);
    __builtin_amdgcn_s_setprio(1);
    MM(b01f, 0);
    MM(b23f, 2);
    __builtin_amdgcn_s_setprio(0);
    asm volatile("s_waitcnt vmcnt(6) lgkmcnt(0)" ::: "memory");
    __builtin_amdgcn_s_barrier();
    const int bn = (bc == 2 * 49152) ? 0 : bc + 49152;
    if (t + 1 < NT) { RDA(bn); RDB01(bn); }
    bc = bn;
    bs = (bs == 2 * 49152) ? 0 : bs + 49152;
  }

  // ---- epilogue: C write (D: col=lane&15, row=(lane>>4)*4+j) ----
  const int r0 = bm0 + wr * 64 + ((lane >> 4) << 2);
  const int c0 = bn0 + wc * 64 + (lane & 15);
  if (OUT_MODE == 3 && bn0 >= 2048) {
    // V columns -> VtOut[b][col-2048][s] (b = row>>11, s = row&2047)
#pragma unroll
    for (int mf = 0; mf < 4; ++mf) {
      const int row0 = r0 + mf * 16;
      const int b = row0 >> 11, s = row0 & 2047;
      unsigned short* Vb = VtOut + (long)b * 2097152;
#pragma unroll
      for (int nf = 0; nf < 4; ++nf) {
        const int col = c0 + nf * 16;
        const float bb = BIAS ? bias[col] : 0.0f;
        f32x4 v = acc[mf][nf];
        ushort4 o;
        o.x = f2bf(v[0] * alpha + bb); o.y = f2bf(v[1] * alpha + bb);
        o.z = f2bf(v[2] * alpha + bb); o.w = f2bf(v[3] * alpha + bb);
        *reinterpret_cast<ushort4*>(Vb + (long)(col - 2048) * 2048 + s) = o;
      }
    }
  } else {
#pragma unroll
    for (int mf = 0; mf < 4; ++mf)
#pragma unroll
      for (int nf = 0; nf < 4; ++nf) {
        const int row0 = r0 + mf * 16;
        const int col = c0 + nf * 16;
        f32x4 v = acc[mf][nf];
        const float bb = BIAS ? bias[col] : 0.0f;
        if (OUT_MODE == 0 || OUT_MODE == 3) {
          unsigned short* C = (unsigned short*)Cv + (long)bz * sC;
#pragma unroll
          for (int j = 0; j < 4; ++j)
            C[(long)(row0 + j) * ldc + col] = f2bf(v[j] * alpha + bb);
        } else {
          float* C = (float*)Cv + (long)bz * sC;
#pragma unroll
          for (int j = 0; j < 4; ++j)
            C[(long)(row0 + j) * ldc + col] = v[j] * alpha + bb;
        }
      }
  }
#undef STG
#undef STG_ALL
#undef RDA
#undef RDB01
#undef RDB23
#undef MM
}

// ---------------- row softmax on bf16 scores, in place ----------------
__global__ __launch_bounds__(256) void k_softmax_bf16(unsigned short* __restrict__ S) {
  long row = blockIdx.x;
  unsigned short* R = S + row * 2048;
  int t = threadIdx.x;
  int wid = t >> 6, lane = t & 63;
  uint4 raw = reinterpret_cast<const uint4*>(R)[t];
  unsigned int w[4] = {raw.x, raw.y, raw.z, raw.w};
  float v[8];
#pragma unroll
  for (int j = 0; j < 4; ++j) {
    v[2 * j]     = __builtin_bit_cast(float, (unsigned int)(w[j] << 16));
    v[2 * j + 1] = __builtin_bit_cast(float, (unsigned int)(w[j] & 0xffff0000u));
  }
  float m = v[0];
#pragma unroll
  for (int j = 1; j < 8; ++j) m = fmaxf(m, v[j]);
#pragma unroll
  for (int off = 32; off >= 1; off >>= 1) m = fmaxf(m, __shfl_xor(m, off));
  __shared__ float red[8];
  if (lane == 0) red[wid] = m;
  __syncthreads();
  m = fmaxf(fmaxf(red[0], red[1]), fmaxf(red[2], red[3]));

  float e[8], s = 0.f;
#pragma unroll
  for (int j = 0; j < 8; ++j) { e[j] = __expf(v[j] - m); s += e[j]; }
#pragma unroll
  for (int off = 32; off >= 1; off >>= 1) s += __shfl_xor(s, off);
  if (lane == 0) red[4 + wid] = s;
  __syncthreads();
  s = red[4] + red[5] + red[6] + red[7];
  float inv = 1.0f / s;

  uint4 o;
  unsigned int* ow = &o.x;
#pragma unroll
  for (int j = 0; j < 4; ++j)
    ow[j] = (unsigned int)f2bf(e[2 * j] * inv) |
            ((unsigned int)f2bf(e[2 * j + 1] * inv) << 16);
  reinterpret_cast<uint4*>(R)[t] = o;
}

extern "C" void kernel_launch(void* const* d_in, const int* in_sizes, int n_in,
                              void* d_out, int out_size, void* d_ws, size_t ws_size,
                              hipStream_t stream) {
  const float* X  = (const float*)d_in[0];
  const float* Wq = (const float*)d_in[1];
  const float* bq = (const float*)d_in[2];
  const float* Wk = (const float*)d_in[3];
  const float* bk = (const float*)d_in[4];
  const float* Wv = (const float*)d_in[5];
  const float* bv = (const float*)d_in[6];
  float* out = (float*)d_out;
  (void)in_sizes; (void)n_in; (void)out_size; (void)ws_size;

  constexpr long S = 2048, H = 1024;
  constexpr long MS = 4 * S;

  size_t off = 0;
  auto alloc = [&](size_t bytes) { char* p = (char*)d_ws + off; off += bytes; return p; };
  unsigned short* Xb    = (unsigned short*)alloc(MS * H * 2);
  unsigned short* Wb    = (unsigned short*)alloc(3 * H * H * 2);
  float*          biasF = (float*)alloc(3 * H * 4);
  unsigned short* QKVb  = (unsigned short*)alloc(MS * 3 * H * 2);
  unsigned short* Vt    = (unsigned short*)alloc(4 * H * S * 2);
  unsigned short* Sb    = (unsigned short*)alloc(4 * S * S * 2);
  (void)Wb;

  // 1) fused converts + bias
  k_prep<<<dim3(11276), 256, 0, stream>>>(X, Wq, Wk, Wv, bq, bk, bv, Xb, biasF);

  // 2) fused QKV = X @ [Wq|Wk|Wv]^T + b; V-cols written transposed to Vt — 768 blocks
  gemm3p<3, 1, 0><<<dim3(12, 64, 1), 512, 0, stream>>>(
      Xb, Xb + MS * H, QKVb, biasF, Vt, 0,
      1024, 1024, 3072, 1024, 1.0f, 0, 0, 0);

  // 3) scores = Q @ K^T / 32 (per batch 2048x2048, K=1024) — 512 blocks, XCD-batch swizzle
  gemm3p<0, 0, 1><<<dim3(512), 512, 0, stream>>>(
      QKVb, QKVb + 1024, Sb, nullptr, nullptr, 8,
      3072, 3072, 2048, 1024, 0.03125f, S * 3 * H, S * 3 * H, S * S);

  // 4) softmax rows in place (bf16)
  k_softmax_bf16<<<dim3((int)MS), 256, 0, stream>>>(Sb);

  // 5) O = P @ V (per batch M=2048, N=1024, K=2048) — 256 blocks, XCD-batch swizzle
  gemm3p<1, 0, 1><<<dim3(256), 512, 0, stream>>>(
      Sb, Vt, out, nullptr, nullptr, 4,
      2048, 2048, 1024, 2048, 1.0f, S * S, H * S, S * H);
}